// Round 2
// baseline (446.349 us; speedup 1.0000x reference)
//
#include <hip/hip_runtime.h>
#include <hip/hip_bf16.h>
#include <math.h>

// ---------------------------------------------------------------------------
// VariationalGATEncoder: 3x GATConv (single head, PyG semantics).
// Round 3 -> 4 change:
//  - Softmax pulled out of the gather loops. New alpha_l1/alpha_cat kernels
//    (wave per dst, scores-only: E x 8B traffic) precompute normalized
//    per-edge weights into packed CSR-ordered records {alpha, src} (8B) /
//    {alphaM, alphaL, src, 0} (16B). Gather kernels are now shuffle-free
//    pure streams: 8 uniform record loads -> 8 independent 512B row gathers
//    -> FMAs. R2's counters (VALU+LDS ~50%, HBM 47%, neither saturated)
//    showed the ds_bpermute chains (3/edge + 24/strip) were the serial
//    bottleneck between memory phases.
// ---------------------------------------------------------------------------

#define NNODES 50000

typedef __attribute__((ext_vector_type(8))) short bf16x8;
typedef __attribute__((ext_vector_type(4))) float f32x4;

__device__ inline float bf2f(unsigned short u) {
    return __uint_as_float(((unsigned int)u) << 16);
}
__device__ inline unsigned short f2bf(float f) {
    unsigned int i = __float_as_uint(f);
    unsigned int r = i + 0x7fffu + ((i >> 16) & 1u);   // RNE
    return (unsigned short)(r >> 16);
}

// ---------------- converts ----------------

__global__ void f32_to_bf16_kernel(const float* __restrict__ in, unsigned short* __restrict__ out, int n4) {
    int i = blockIdx.x * blockDim.x + threadIdx.x;
    if (i < n4) {
        float4 v = ((const float4*)in)[i];
        ushort4 o;
        o.x = f2bf(v.x); o.y = f2bf(v.y); o.z = f2bf(v.z); o.w = f2bf(v.w);
        ((ushort4*)out)[i] = o;
    }
}

// Wt[n][k] = bf16(W[k][n]); W is [K x Nc] row-major. grid=Nc blocks, block=K threads.
__global__ void transpose_w_kernel(const float* __restrict__ W, unsigned short* __restrict__ Wt, int K, int Nc) {
    int n = blockIdx.x, k = threadIdx.x;
    Wt[(size_t)n * K + k] = f2bf(W[(size_t)k * Nc + n]);
}

// Wt (256 x 256): rows 0..127 = W_mu^T, rows 128..255 = W_ls^T. K=256, each head Nc=128.
__global__ void transpose_wcat_kernel(const float* __restrict__ Wmu, const float* __restrict__ Wls,
                                      unsigned short* __restrict__ Wt) {
    int n = blockIdx.x, k = threadIdx.x;
    float v = (n < 128) ? Wmu[(size_t)k * 128 + n] : Wls[(size_t)k * 128 + (n - 128)];
    Wt[(size_t)n * 256 + k] = f2bf(v);
}

// ---------------- CSR build ----------------

__global__ void count_edges(const int* __restrict__ dst, int E, int* __restrict__ cnt) {
    int e = blockIdx.x * blockDim.x + threadIdx.x;
    if (e < E) atomicAdd(&cnt[dst[e]], 1);
}

__global__ void scan_partial(const int* __restrict__ cnt, int* __restrict__ row_start,
                             int* __restrict__ bsum, int N) {
    __shared__ int wsum[16];
    int t = threadIdx.x;
    int gi = blockIdx.x * 1024 + t;
    int lane = t & 63, wid = t >> 6;
    int v = (gi < N) ? cnt[gi] : 0;
    int x = v;
    for (int off = 1; off < 64; off <<= 1) {
        int u = __shfl_up(x, off);
        if (lane >= off) x += u;
    }
    if (lane == 63) wsum[wid] = x;
    __syncthreads();
    if (wid == 0) {
        int s = (lane < 16) ? wsum[lane] : 0;
        for (int off = 1; off < 16; off <<= 1) {
            int u = __shfl_up(s, off);
            if (lane >= off) s += u;
        }
        if (lane < 16) wsum[lane] = s;
    }
    __syncthreads();
    int waveoff = (wid == 0) ? 0 : wsum[wid - 1];
    if (gi < N) row_start[gi] = waveoff + x - v;
    if (t == 1023) bsum[blockIdx.x] = waveoff + x;
}

__global__ void scan_bsum(int* __restrict__ bsum, int nb) {   // one wave, nb <= 64
    int lane = threadIdx.x;
    int v = (lane < nb) ? bsum[lane] : 0;
    int x = v;
    for (int off = 1; off < 64; off <<= 1) {
        int u = __shfl_up(x, off);
        if (lane >= off) x += u;
    }
    if (lane < nb) bsum[lane] = x - v;   // exclusive
}

__global__ void scan_add(int* __restrict__ row_start, const int* __restrict__ bsum, int N, int E) {
    int gi = blockIdx.x * 1024 + threadIdx.x;
    if (gi < N) row_start[gi] += bsum[blockIdx.x];
    if (gi == 0) row_start[N] = E;
}

__global__ void scatter_edges(const int* __restrict__ src, const int* __restrict__ dst, int E,
                              const int* __restrict__ row_start, int* __restrict__ cursor,
                              int* __restrict__ sperm) {
    int e = blockIdx.x * blockDim.x + threadIdx.x;
    if (e < E) {
        int d = dst[e];
        int pos = row_start[d] + atomicAdd(&cursor[d], 1);
        sperm[pos] = src[e];
    }
}

// ---------------- bf16 MFMA GEMM ----------------
// C[M,Cout](bf16) = A[M,K](bf16) @ Bt[Cout,K](bf16)^T, fp32 accumulate.
// 128x128 tile, BK=32, 256 threads (4 waves, 2x2 of 64x64 each).

__global__ __launch_bounds__(256) void mfma_gemm(const unsigned short* __restrict__ A,
                                                 const unsigned short* __restrict__ Bt,
                                                 unsigned short* __restrict__ C_,
                                                 int M, int K, int Cout) {
    __shared__ __align__(16) unsigned short As[128 * 40];  // rows padded to 40 (80B): 2-way max
    __shared__ __align__(16) unsigned short Bs[128 * 40];
    int t = threadIdx.x;
    int lane = t & 63, w = t >> 6;
    int wm = w & 1, wn = w >> 1;
    int l15 = lane & 15, quad = lane >> 4;
    int mbase = blockIdx.x * 128, nbase = blockIdx.y * 128;

    f32x4 acc[4][4];
    const f32x4 zero = {0.f, 0.f, 0.f, 0.f};
#pragma unroll
    for (int mt = 0; mt < 4; mt++)
#pragma unroll
        for (int nt = 0; nt < 4; nt++) acc[mt][nt] = zero;

    for (int k0 = 0; k0 < K; k0 += 32) {
#pragma unroll
        for (int i = t; i < 512; i += 256) {
            int row = i >> 2, seg = i & 3;
            int gr = mbase + row;
            float4 va = make_float4(0.f, 0.f, 0.f, 0.f);
            if (gr < M) va = *(const float4*)(A + (size_t)gr * K + k0 + seg * 8);
            *(float4*)(&As[row * 40 + seg * 8]) = va;
            float4 vb = *(const float4*)(Bt + (size_t)(nbase + row) * K + k0 + seg * 8);
            *(float4*)(&Bs[row * 40 + seg * 8]) = vb;
        }
        __syncthreads();
        bf16x8 af[4], bfr[4];
#pragma unroll
        for (int mt = 0; mt < 4; mt++)
            af[mt] = *(const bf16x8*)(&As[(wm * 64 + mt * 16 + l15) * 40 + quad * 8]);
#pragma unroll
        for (int nt = 0; nt < 4; nt++)
            bfr[nt] = *(const bf16x8*)(&Bs[(wn * 64 + nt * 16 + l15) * 40 + quad * 8]);
#pragma unroll
        for (int mt = 0; mt < 4; mt++)
#pragma unroll
            for (int nt = 0; nt < 4; nt++)
                acc[mt][nt] = __builtin_amdgcn_mfma_f32_16x16x32_bf16(af[mt], bfr[nt], acc[mt][nt], 0, 0, 0);
        __syncthreads();
    }
    // epilogue: C/D layout col=lane&15, row=quad*4+reg (m89-verified)
#pragma unroll
    for (int mt = 0; mt < 4; mt++) {
#pragma unroll
        for (int nt = 0; nt < 4; nt++) {
#pragma unroll
            for (int r = 0; r < 4; r++) {
                int m = mbase + wm * 64 + mt * 16 + quad * 4 + r;
                int n = nbase + wn * 64 + nt * 16 + l15;
                if (m < M) C_[(size_t)m * Cout + n] = f2bf(acc[mt][nt][r]);
            }
        }
    }
}

// ---------------- scores ----------------

__global__ __launch_bounds__(256) void scores_l1(const unsigned short* __restrict__ h,
                                                 const float* __restrict__ a_src,
                                                 const float* __restrict__ a_dst,
                                                 float* __restrict__ ssrc,
                                                 float* __restrict__ sdst, int N) {
    int wave = threadIdx.x >> 6, lane = threadIdx.x & 63;
    int row = blockIdx.x * 4 + wave;
    if (row >= N) return;
    ushort4 u = *(const ushort4*)(h + (size_t)row * 256 + lane * 4);
    float h0 = bf2f(u.x), h1 = bf2f(u.y), h2 = bf2f(u.z), h3 = bf2f(u.w);
    float4 av = ((const float4*)a_src)[lane];
    float4 dv = ((const float4*)a_dst)[lane];
    float ss = h0 * av.x + h1 * av.y + h2 * av.z + h3 * av.w;
    float sd = h0 * dv.x + h1 * dv.y + h2 * dv.z + h3 * dv.w;
    for (int off = 32; off; off >>= 1) {
        ss += __shfl_xor(ss, off);
        sd += __shfl_xor(sd, off);
    }
    if (lane == 0) {
        ssrc[row] = ss;
        sdst[row] = sd;
    }
}

// lanes 0..31 -> mu head (channels lane*4..+3), lanes 32..63 -> logstd head.
__global__ __launch_bounds__(256) void scores_cat(const unsigned short* __restrict__ hcat,
                                                  const float* __restrict__ a_src_mu, const float* __restrict__ a_dst_mu,
                                                  const float* __restrict__ a_src_ls, const float* __restrict__ a_dst_ls,
                                                  float* __restrict__ sm_s, float* __restrict__ sm_d,
                                                  float* __restrict__ sl_s, float* __restrict__ sl_d, int N) {
    int wave = threadIdx.x >> 6, lane = threadIdx.x & 63;
    int row = blockIdx.x * 4 + wave;
    if (row >= N) return;
    ushort4 u = *(const ushort4*)(hcat + (size_t)row * 256 + lane * 4);
    float h0 = bf2f(u.x), h1 = bf2f(u.y), h2 = bf2f(u.z), h3 = bf2f(u.w);
    bool isMu = lane < 32;
    const float* as = isMu ? a_src_mu : a_src_ls;
    const float* ad = isMu ? a_dst_mu : a_dst_ls;
    int c = (lane & 31) * 4;
    float4 av = *(const float4*)(as + c);
    float4 dv = *(const float4*)(ad + c);
    float ss = h0 * av.x + h1 * av.y + h2 * av.z + h3 * av.w;
    float sd = h0 * dv.x + h1 * dv.y + h2 * dv.z + h3 * dv.w;
    for (int off = 16; off; off >>= 1) {   // reduce within each 32-lane half
        ss += __shfl_xor(ss, off);
        sd += __shfl_xor(sd, off);
    }
    if ((lane & 31) == 0) {
        if (isMu) { sm_s[row] = ss; sm_d[row] = sd; }
        else      { sl_s[row] = ss; sl_d[row] = sd; }
    }
}

// ---------------- alpha precompute ----------------
// Wave per dst node: segment softmax over incoming edges, scores-only traffic.
// Writes CSR-ordered packed records so the gather kernels are shuffle-free.
// rec_l1[e] = {float alpha; int src} (int2), rec_cat[e] = {aM, aL, src, 0} (int4).

__global__ __launch_bounds__(256) void alpha_l1(const float* __restrict__ ssrc,
                                                const float* __restrict__ sdst,
                                                const int* __restrict__ row_start,
                                                const int* __restrict__ sperm,
                                                int2* __restrict__ rec, int N) {
    int wave = threadIdx.x >> 6, lane = threadIdx.x & 63;
    int node = blockIdx.x * 4 + wave;
    if (node >= N) return;
    int begin = row_start[node], end = row_start[node + 1];
    int deg = end - begin;
    if (deg <= 0) return;
    float sd = sdst[node];
    if (deg <= 64) {                       // fast path (mean degree ~16)
        int idx = begin + lane;
        bool valid = lane < deg;
        int s = valid ? sperm[idx] : 0;
        float e = -INFINITY;
        if (valid) {
            float t = ssrc[s] + sd;
            e = (t > 0.f) ? t : 0.2f * t;
        }
        float m = e;
        for (int off = 32; off; off >>= 1) m = fmaxf(m, __shfl_xor(m, off));
        float p = valid ? __expf(e - m) : 0.f;
        float z = p;
        for (int off = 32; off; off >>= 1) z += __shfl_xor(z, off);
        if (valid) rec[idx] = make_int2(__float_as_int(p / (z + 1e-16f)), s);
    } else {                               // generic 3-pass (rare)
        float m = -INFINITY;
        for (int j0 = begin; j0 < end; j0 += 64) {
            int idx = j0 + lane;
            float e = -INFINITY;
            if (idx < end) {
                float t = ssrc[sperm[idx]] + sd;
                e = (t > 0.f) ? t : 0.2f * t;
            }
            for (int off = 32; off; off >>= 1) e = fmaxf(e, __shfl_xor(e, off));
            m = fmaxf(m, e);
        }
        float z = 0.f;
        for (int j0 = begin; j0 < end; j0 += 64) {
            int idx = j0 + lane;
            float p = 0.f;
            int s = 0;
            if (idx < end) {
                s = sperm[idx];
                float t = ssrc[s] + sd;
                float e = (t > 0.f) ? t : 0.2f * t;
                p = __expf(e - m);
                rec[idx] = make_int2(__float_as_int(p), s);
            }
            float ps = p;
            for (int off = 32; off; off >>= 1) ps += __shfl_xor(ps, off);
            z += ps;
        }
        float invz = 1.f / (z + 1e-16f);
        for (int j0 = begin; j0 < end; j0 += 64) {
            int idx = j0 + lane;
            if (idx < end) {
                int2 v = rec[idx];
                v.x = __float_as_int(__int_as_float(v.x) * invz);
                rec[idx] = v;
            }
        }
    }
}

__global__ __launch_bounds__(256) void alpha_cat(const float* __restrict__ sm_s, const float* __restrict__ sm_d,
                                                 const float* __restrict__ sl_s, const float* __restrict__ sl_d,
                                                 const int* __restrict__ row_start,
                                                 const int* __restrict__ sperm,
                                                 int4* __restrict__ rec, int N) {
    int wave = threadIdx.x >> 6, lane = threadIdx.x & 63;
    int node = blockIdx.x * 4 + wave;
    if (node >= N) return;
    int begin = row_start[node], end = row_start[node + 1];
    int deg = end - begin;
    if (deg <= 0) return;
    float sdm = sm_d[node], sdl = sl_d[node];
    if (deg <= 64) {
        int idx = begin + lane;
        bool valid = lane < deg;
        int s = valid ? sperm[idx] : 0;
        float eM = -INFINITY, eL = -INFINITY;
        if (valid) {
            float tM = sm_s[s] + sdm;
            eM = (tM > 0.f) ? tM : 0.2f * tM;
            float tL = sl_s[s] + sdl;
            eL = (tL > 0.f) ? tL : 0.2f * tL;
        }
        float mM = eM, mL = eL;
        for (int off = 32; off; off >>= 1) {
            mM = fmaxf(mM, __shfl_xor(mM, off));
            mL = fmaxf(mL, __shfl_xor(mL, off));
        }
        float pM = valid ? __expf(eM - mM) : 0.f;
        float pL = valid ? __expf(eL - mL) : 0.f;
        float zM = pM, zL = pL;
        for (int off = 32; off; off >>= 1) {
            zM += __shfl_xor(zM, off);
            zL += __shfl_xor(zL, off);
        }
        if (valid)
            rec[idx] = make_int4(__float_as_int(pM / (zM + 1e-16f)),
                                 __float_as_int(pL / (zL + 1e-16f)), s, 0);
    } else {
        float mM = -INFINITY, mL = -INFINITY;
        for (int j0 = begin; j0 < end; j0 += 64) {
            int idx = j0 + lane;
            float eM = -INFINITY, eL = -INFINITY;
            if (idx < end) {
                int s = sperm[idx];
                float tM = sm_s[s] + sdm;
                eM = (tM > 0.f) ? tM : 0.2f * tM;
                float tL = sl_s[s] + sdl;
                eL = (tL > 0.f) ? tL : 0.2f * tL;
            }
            for (int off = 32; off; off >>= 1) {
                eM = fmaxf(eM, __shfl_xor(eM, off));
                eL = fmaxf(eL, __shfl_xor(eL, off));
            }
            mM = fmaxf(mM, eM);
            mL = fmaxf(mL, eL);
        }
        float zM = 0.f, zL = 0.f;
        for (int j0 = begin; j0 < end; j0 += 64) {
            int idx = j0 + lane;
            float pM = 0.f, pL = 0.f;
            int s = 0;
            if (idx < end) {
                s = sperm[idx];
                float tM = sm_s[s] + sdm;
                float eM = (tM > 0.f) ? tM : 0.2f * tM;
                float tL = sl_s[s] + sdl;
                float eL = (tL > 0.f) ? tL : 0.2f * tL;
                pM = __expf(eM - mM);
                pL = __expf(eL - mL);
                rec[idx] = make_int4(__float_as_int(pM), __float_as_int(pL), s, 0);
            }
            float psM = pM, psL = pL;
            for (int off = 32; off; off >>= 1) {
                psM += __shfl_xor(psM, off);
                psL += __shfl_xor(psL, off);
            }
            zM += psM; zL += psL;
        }
        float izM = 1.f / (zM + 1e-16f), izL = 1.f / (zL + 1e-16f);
        for (int j0 = begin; j0 < end; j0 += 64) {
            int idx = j0 + lane;
            if (idx < end) {
                int4 v = rec[idx];
                v.x = __float_as_int(__int_as_float(v.x) * izM);
                v.y = __float_as_int(__int_as_float(v.y) * izL);
                rec[idx] = v;
            }
        }
    }
}

// ---------------- gather (pure streaming, shuffle-free) ----------------
// Wave per dst node. Per 8-edge group: 8 wave-uniform record loads then
// 8 independent 512B row gathers in flight, then FMAs. Tail is branch-free:
// record index clamped to end-1, weight zeroed for idx >= end.

__global__ __launch_bounds__(256) void gather_l1(const unsigned short* __restrict__ h,
                                                 const int2* __restrict__ rec,
                                                 const int* __restrict__ row_start,
                                                 const float* __restrict__ bias,
                                                 unsigned short* __restrict__ out, int N) {
    int wave = threadIdx.x >> 6, lane = threadIdx.x & 63;
    int node = blockIdx.x * 4 + wave;
    if (node >= N) return;
    int begin = row_start[node], end = row_start[node + 1];
    float acc0 = 0.f, acc1 = 0.f, acc2 = 0.f, acc3 = 0.f;

    for (int j = begin; j < end; j += 8) {
        int2 r[8];
#pragma unroll
        for (int i = 0; i < 8; i++) {
            int idx = j + i;
            r[i] = rec[idx < end ? idx : end - 1];
        }
        ushort4 u[8];
#pragma unroll
        for (int i = 0; i < 8; i++)
            u[i] = *(const ushort4*)(h + (size_t)r[i].y * 256 + lane * 4);
#pragma unroll
        for (int i = 0; i < 8; i++) {
            float p = (j + i < end) ? __int_as_float(r[i].x) : 0.f;
            acc0 += p * bf2f(u[i].x);
            acc1 += p * bf2f(u[i].y);
            acc2 += p * bf2f(u[i].z);
            acc3 += p * bf2f(u[i].w);
        }
    }
    float4 bv = ((const float4*)bias)[lane];
    ushort4 o;
    o.x = f2bf(fmaxf(acc0 + bv.x, 0.f));
    o.y = f2bf(fmaxf(acc1 + bv.y, 0.f));
    o.z = f2bf(fmaxf(acc2 + bv.z, 0.f));
    o.w = f2bf(fmaxf(acc3 + bv.w, 0.f));
    *(ushort4*)(out + (size_t)node * 256 + lane * 4) = o;
}

// lanes 0..31 accumulate mu channels (hcat cols 0..127), 32..63 logstd (128..255).
__global__ __launch_bounds__(256) void gather_cat(const unsigned short* __restrict__ hcat,
                                                  const int4* __restrict__ rec,
                                                  const int* __restrict__ row_start,
                                                  const float* __restrict__ b_mu, const float* __restrict__ b_ls,
                                                  float* __restrict__ out_mu, float* __restrict__ out_ls, int N) {
    int wave = threadIdx.x >> 6, lane = threadIdx.x & 63;
    int node = blockIdx.x * 4 + wave;
    if (node >= N) return;
    int begin = row_start[node], end = row_start[node + 1];
    bool isMu = lane < 32;
    float acc0 = 0.f, acc1 = 0.f, acc2 = 0.f, acc3 = 0.f;

    for (int j = begin; j < end; j += 8) {
        int4 r[8];
#pragma unroll
        for (int i = 0; i < 8; i++) {
            int idx = j + i;
            r[i] = rec[idx < end ? idx : end - 1];
        }
        ushort4 u[8];
#pragma unroll
        for (int i = 0; i < 8; i++)
            u[i] = *(const ushort4*)(hcat + (size_t)r[i].z * 256 + lane * 4);
#pragma unroll
        for (int i = 0; i < 8; i++) {
            float p = isMu ? __int_as_float(r[i].x) : __int_as_float(r[i].y);
            p = (j + i < end) ? p : 0.f;
            acc0 += p * bf2f(u[i].x);
            acc1 += p * bf2f(u[i].y);
            acc2 += p * bf2f(u[i].z);
            acc3 += p * bf2f(u[i].w);
        }
    }
    int c = (lane & 31) * 4;
    float4 bv = *(const float4*)((isMu ? b_mu : b_ls) + c);
    float4 o = make_float4(acc0 + bv.x, acc1 + bv.y, acc2 + bv.z, acc3 + bv.w);
    float* dstp = isMu ? (out_mu + (size_t)node * 128 + c) : (out_ls + (size_t)node * 128 + c);
    *(float4*)dstp = o;
}

// ---------------- launch ----------------

extern "C" void kernel_launch(void* const* d_in, const int* in_sizes, int n_in,
                              void* d_out, int out_size, void* d_ws, size_t ws_size,
                              hipStream_t stream) {
    const int N = NNODES;
    const float* x      = (const float*)d_in[0];
    const int*   ei     = (const int*)d_in[1];
    const int    E      = in_sizes[1] / 2;
    const int*   src    = ei;
    const int*   dst    = ei + E;
    const float* W1     = (const float*)d_in[2];
    const float* a_src1 = (const float*)d_in[3];
    const float* a_dst1 = (const float*)d_in[4];
    const float* b1     = (const float*)d_in[5];
    const float* W_mu   = (const float*)d_in[6];
    const float* a_src_mu = (const float*)d_in[7];
    const float* a_dst_mu = (const float*)d_in[8];
    const float* b_mu   = (const float*)d_in[9];
    const float* W_ls   = (const float*)d_in[10];
    const float* a_src_ls = (const float*)d_in[11];
    const float* a_dst_ls = (const float*)d_in[12];
    const float* b_ls   = (const float*)d_in[13];

    const size_t NM = (size_t)N * 256;   // 12.8M elems

    // workspace layout (16B-aligned blocks first)
    char* w = (char*)d_ws;
    unsigned short* xb   = (unsigned short*)w;              w += NM * 2;
    unsigned short* hlin = (unsigned short*)w;              w += NM * 2;
    unsigned short* h    = (unsigned short*)w;              w += NM * 2;
    unsigned short* hcat = (unsigned short*)w;              w += NM * 2;
    unsigned short* W1t  = (unsigned short*)w;              w += 256 * 256 * 2;
    unsigned short* Wct  = (unsigned short*)w;              w += 256 * 256 * 2;
    int2* rec1 = (int2*)w;     w += (size_t)E * 8;
    int4* recc = (int4*)w;     w += (size_t)E * 16;
    float* s1s = (float*)w;  w += N * 4;
    float* s1d = (float*)w;  w += N * 4;
    float* sms = (float*)w;  w += N * 4;
    float* smd = (float*)w;  w += N * 4;
    float* sls = (float*)w;  w += N * 4;
    float* sld = (float*)w;  w += N * 4;
    int* row_start = (int*)w;  w += (N + 1) * 4;
    int* cnt = (int*)w;        w += N * 4;
    int* bsum = (int*)w;       w += 64 * 4;
    int* sperm = (int*)w;      w += (size_t)E * 4;

    const int egrid = (E + 255) / 256;
    const int ngrid4 = (N + 3) / 4;               // 12500
    const int nb1024 = (N + 1023) / 1024;         // 49
    const int mtiles = (N + 127) / 128;           // 391

    // ---- converts ----
    f32_to_bf16_kernel<<<(int)((NM / 4 + 255) / 256), 256, 0, stream>>>(x, xb, (int)(NM / 4));
    transpose_w_kernel<<<256, 256, 0, stream>>>(W1, W1t, 256, 256);
    transpose_wcat_kernel<<<256, 256, 0, stream>>>(W_mu, W_ls, Wct);

    // ---- CSR build (once; shared by all 3 layers) ----
    hipMemsetAsync(cnt, 0, N * sizeof(int), stream);
    count_edges<<<egrid, 256, 0, stream>>>(dst, E, cnt);
    scan_partial<<<nb1024, 1024, 0, stream>>>(cnt, row_start, bsum, N);
    scan_bsum<<<1, 64, 0, stream>>>(bsum, nb1024);
    scan_add<<<nb1024, 1024, 0, stream>>>(row_start, bsum, N, E);
    hipMemsetAsync(cnt, 0, N * sizeof(int), stream);
    scatter_edges<<<egrid, 256, 0, stream>>>(src, dst, E, row_start, cnt, sperm);

    // ---- layer 1: x -> h (relu) ----
    mfma_gemm<<<dim3(mtiles, 2), 256, 0, stream>>>(xb, W1t, hlin, N, 256, 256);
    scores_l1<<<ngrid4, 256, 0, stream>>>(hlin, a_src1, a_dst1, s1s, s1d, N);
    alpha_l1<<<ngrid4, 256, 0, stream>>>(s1s, s1d, row_start, sperm, rec1, N);
    gather_l1<<<ngrid4, 256, 0, stream>>>(hlin, rec1, row_start, b1, h, N);

    // ---- fused mu/logstd head ----
    mfma_gemm<<<dim3(mtiles, 2), 256, 0, stream>>>(h, Wct, hcat, N, 256, 256);
    scores_cat<<<ngrid4, 256, 0, stream>>>(hcat, a_src_mu, a_dst_mu, a_src_ls, a_dst_ls,
                                           sms, smd, sls, sld, N);
    alpha_cat<<<ngrid4, 256, 0, stream>>>(sms, smd, sls, sld, row_start, sperm, recc, N);
    float* out_mu = (float*)d_out;
    float* out_ls = out_mu + (size_t)N * 128;
    gather_cat<<<ngrid4, 256, 0, stream>>>(hcat, recc, row_start, b_mu, b_ls,
                                           out_mu, out_ls, N);
}